// Round 1
// baseline (574.807 us; speedup 1.0000x reference)
//
#include <hip/hip_runtime.h>
#include <hip/hip_bf16.h>

#define HIDDEN 896
#define HEADS 7
#define HDIM 128
#define BB 4
#define TT 2048
#define MTOT (BB*TT)   // 8192

typedef short bf16x8 __attribute__((ext_vector_type(8)));
typedef float f32x4 __attribute__((ext_vector_type(4)));

__device__ __forceinline__ short f2bf(float f) {
    union { float f; unsigned u; } v; v.f = f;
    unsigned r = (v.u + 0x7FFF + ((v.u >> 16) & 1)) >> 16;
    return (short)r;
}

// ---------------- kernel 1: cast x (fp32) -> bf16 ----------------
__global__ __launch_bounds__(256) void cast_x_kernel(const float* __restrict__ x,
                                                     short* __restrict__ xb) {
    int idx = blockIdx.x * blockDim.x + threadIdx.x;
    int base = idx * 4;
    if (base < MTOT * HIDDEN) {
        float4 v = *(const float4*)(x + base);
        short4 o;
        o.x = f2bf(v.x); o.y = f2bf(v.y); o.z = f2bf(v.z); o.w = f2bf(v.w);
        *(short4*)(xb + base) = o;
    }
}

// ---------------- kernel 2: QKV projection GEMM ----------------
// C[m][n] = sum_k xb[m][k] * W[k][n]   (W per head, [896][128] row-major)
// grid: (M/64=128, N/64=2, heads*3=21), block 256 (4 waves, 2x2 of 32x32)
__global__ __launch_bounds__(256) void qkv_gemm(
    const short* __restrict__ xb,
    const float* __restrict__ Wq, const float* __restrict__ Wk, const float* __restrict__ Wv,
    short* __restrict__ Q, short* __restrict__ Kk, short* __restrict__ Vt)
{
    __shared__ short Ash[64 * 40];
    __shared__ short Bsh[64 * 40];
    const int m0 = blockIdx.x * 64;
    const int n0 = blockIdx.y * 64;
    const int z = blockIdx.z;
    const int head = z / 3, type = z % 3;
    const float* W = (type == 0 ? Wq : (type == 1 ? Wk : Wv)) + head * (HIDDEN * HDIM);

    const int tid = threadIdx.x;
    const int wave = tid >> 6, lane = tid & 63;
    const int quad = lane >> 4, l16 = lane & 15;
    const int wm = (wave >> 1) * 32, wn = (wave & 1) * 32;

    f32x4 acc[2][2] = {};

    const int ar = tid >> 2, ac = (tid & 3) * 8;        // A staging: row, col-chunk
    const int kr0 = tid >> 4, nc0 = (tid & 15) * 4;     // B staging elem 0
    const int kr1 = (tid + 256) >> 4, nc1 = (tid & 15) * 4;

    for (int k0 = 0; k0 < HIDDEN; k0 += 32) {
        bf16x8 av = *(const bf16x8*)(xb + (m0 + ar) * HIDDEN + k0 + ac);
        float4 bv0 = *(const float4*)(W + (k0 + kr0) * HDIM + n0 + nc0);
        float4 bv1 = *(const float4*)(W + (k0 + kr1) * HDIM + n0 + nc1);
        __syncthreads();
        *(bf16x8*)(Ash + ar * 40 + ac) = av;
        Bsh[(nc0 + 0) * 40 + kr0] = f2bf(bv0.x);
        Bsh[(nc0 + 1) * 40 + kr0] = f2bf(bv0.y);
        Bsh[(nc0 + 2) * 40 + kr0] = f2bf(bv0.z);
        Bsh[(nc0 + 3) * 40 + kr0] = f2bf(bv0.w);
        Bsh[(nc1 + 0) * 40 + kr1] = f2bf(bv1.x);
        Bsh[(nc1 + 1) * 40 + kr1] = f2bf(bv1.y);
        Bsh[(nc1 + 2) * 40 + kr1] = f2bf(bv1.z);
        Bsh[(nc1 + 3) * 40 + kr1] = f2bf(bv1.w);
        __syncthreads();
        bf16x8 af0 = *(const bf16x8*)(Ash + (wm + l16) * 40 + quad * 8);
        bf16x8 af1 = *(const bf16x8*)(Ash + (wm + 16 + l16) * 40 + quad * 8);
        bf16x8 bf0 = *(const bf16x8*)(Bsh + (wn + l16) * 40 + quad * 8);
        bf16x8 bf1 = *(const bf16x8*)(Bsh + (wn + 16 + l16) * 40 + quad * 8);
        acc[0][0] = __builtin_amdgcn_mfma_f32_16x16x32_bf16(af0, bf0, acc[0][0], 0, 0, 0);
        acc[0][1] = __builtin_amdgcn_mfma_f32_16x16x32_bf16(af0, bf1, acc[0][1], 0, 0, 0);
        acc[1][0] = __builtin_amdgcn_mfma_f32_16x16x32_bf16(af1, bf0, acc[1][0], 0, 0, 0);
        acc[1][1] = __builtin_amdgcn_mfma_f32_16x16x32_bf16(af1, bf1, acc[1][1], 0, 0, 0);
    }

    const int base = head * (MTOT * HDIM);
    for (int mi = 0; mi < 2; mi++)
        for (int ni = 0; ni < 2; ni++)
            for (int r = 0; r < 4; r++) {
                int m = m0 + wm + mi * 16 + quad * 4 + r;
                int n = n0 + wn + ni * 16 + l16;
                short v = f2bf(acc[mi][ni][r]);
                if (type == 0) {
                    Q[base + m * HDIM + n] = v;
                } else if (type == 1) {
                    Kk[base + m * HDIM + n] = v;
                } else {
                    int bb = m >> 11, t = m & 2047;
                    Vt[base + bb * (HDIM * TT) + n * TT + t] = v;
                }
            }
}

// ---------------- kernel 3: fano flash attention ----------------
// grid: (T/64=32, B=4, HEADS=7), block 256 (4 waves, each owns 16 q-rows)
__global__ __launch_bounds__(256) void fano_attn(
    const short* __restrict__ Q, const short* __restrict__ K, const short* __restrict__ Vt,
    short* __restrict__ Ocat, const int* __restrict__ iscp)
{
    __shared__ short Qs[64 * 136];
    __shared__ short Ks[64 * 136];
    __shared__ short Vs[128 * 72];
    __shared__ short Ps[4][16 * 72];

    const int q0 = blockIdx.x * 64;
    const int b = blockIdx.y, h = blockIdx.z;
    const int causal = *iscp;
    const int tid = threadIdx.x, wave = tid >> 6, lane = tid & 63;
    const int quad = lane >> 4, l16 = lane & 15;
    const float scale = 0.08838834764831845f;

    const short* Qbase = Q + (size_t)(h * MTOT + b * TT + q0) * HDIM;
    const short* Kbase0 = K + (size_t)(h * MTOT + b * TT) * HDIM;
    const short* Vbase0 = Vt + (size_t)h * MTOT * HDIM + (size_t)b * HDIM * TT;

    // load Q tile (64 x 128)
    for (int rr = 0; rr < 4; rr++) {
        int e = tid + rr * 256;
        int row = e >> 4, col = (e & 15) * 8;
        *(bf16x8*)(Qs + row * 136 + col) = *(const bf16x8*)(Qbase + row * HDIM + col);
    }
    __syncthreads();
    bf16x8 qf[4];
    for (int ks = 0; ks < 4; ks++)
        qf[ks] = *(const bf16x8*)(Qs + (wave * 16 + l16) * 136 + ks * 32 + quad * 8);

    float mrun[4], lrun[4];
    f32x4 oacc[8] = {};
    int irow[4];
    for (int r = 0; r < 4; r++) {
        mrun[r] = -1e30f; lrun[r] = 0.f;
        irow[r] = q0 + wave * 16 + quad * 4 + r;
    }

    const int send = causal ? (q0 + 64) : TT;
    for (int s0 = 0; s0 < send; s0 += 64) {
        __syncthreads();
        // K tile (64 x 128)
        for (int rr = 0; rr < 4; rr++) {
            int e = tid + rr * 256;
            int row = e >> 4, col = (e & 15) * 8;
            *(bf16x8*)(Ks + row * 136 + col) =
                *(const bf16x8*)(Kbase0 + (size_t)(s0 + row) * HDIM + col);
        }
        // V^T tile (128 x 64)
        for (int rr = 0; rr < 4; rr++) {
            int e = tid + rr * 256;
            int d = e >> 3, c = (e & 7) * 8;
            *(bf16x8*)(Vs + d * 72 + c) = *(const bf16x8*)(Vbase0 + (size_t)d * TT + s0 + c);
        }
        __syncthreads();

        // S = Q K^T
        f32x4 sacc[4] = {};
        for (int ni = 0; ni < 4; ni++)
            for (int ks = 0; ks < 4; ks++) {
                bf16x8 bk = *(const bf16x8*)(Ks + (ni * 16 + l16) * 136 + ks * 32 + quad * 8);
                sacc[ni] = __builtin_amdgcn_mfma_f32_16x16x32_bf16(qf[ks], bk, sacc[ni], 0, 0, 0);
            }

        // scale + fano mask + row max
        float mx[4] = {-1e30f, -1e30f, -1e30f, -1e30f};
        for (int ni = 0; ni < 4; ni++) {
            int s = s0 + ni * 16 + l16;
            int d7 = (s - h + 7) % 7;
            bool line = (d7 == 0) | (d7 == 1) | (d7 == 3);
            for (int r = 0; r < 4; r++) {
                int i = irow[r];
                bool ok = causal ? (s <= i && (line || s >= i - 16))
                                 : (line || (s >= i - 16 && s <= i + 16));
                float v = ok ? (sacc[ni][r] * scale) : -1e30f;
                sacc[ni][r] = v;
                mx[r] = fmaxf(mx[r], v);
            }
        }
        for (int off = 1; off < 16; off <<= 1)
            for (int r = 0; r < 4; r++) mx[r] = fmaxf(mx[r], __shfl_xor(mx[r], off));

        float alpha[4], rs[4];
        for (int r = 0; r < 4; r++) {
            float nm = fmaxf(mrun[r], mx[r]);
            alpha[r] = __expf(mrun[r] - nm);
            mrun[r] = nm;
            rs[r] = 0.f;
        }
        for (int ni = 0; ni < 4; ni++)
            for (int r = 0; r < 4; r++) {
                float p = __expf(sacc[ni][r] - mrun[r]);
                sacc[ni][r] = p;
                rs[r] += p;
            }
        for (int off = 1; off < 16; off <<= 1)
            for (int r = 0; r < 4; r++) rs[r] += __shfl_xor(rs[r], off);
        for (int r = 0; r < 4; r++) lrun[r] = lrun[r] * alpha[r] + rs[r];
        for (int nj = 0; nj < 8; nj++)
            for (int r = 0; r < 4; r++) oacc[nj][r] *= alpha[r];

        // P: C-layout regs -> LDS -> A-layout frags
        short* Pw = &Ps[wave][0];
        for (int ni = 0; ni < 4; ni++)
            for (int r = 0; r < 4; r++)
                Pw[(quad * 4 + r) * 72 + ni * 16 + l16] = f2bf(sacc[ni][r]);
        __syncthreads();

        // O += P V
        for (int ks2 = 0; ks2 < 2; ks2++) {
            bf16x8 ap = *(const bf16x8*)(Pw + l16 * 72 + ks2 * 32 + quad * 8);
            for (int nj = 0; nj < 8; nj++) {
                bf16x8 bv = *(const bf16x8*)(Vs + (nj * 16 + l16) * 72 + ks2 * 32 + quad * 8);
                oacc[nj] = __builtin_amdgcn_mfma_f32_16x16x32_bf16(ap, bv, oacc[nj], 0, 0, 0);
            }
        }
    }

    // epilogue: O /= l, write concat output (bf16)
    short* Obase = Ocat + (size_t)(b * TT) * HIDDEN + h * HDIM;
    for (int nj = 0; nj < 8; nj++)
        for (int r = 0; r < 4; r++) {
            float v = oacc[nj][r] / lrun[r];
            Obase[(size_t)irow[r] * HIDDEN + nj * 16 + l16] = f2bf(v);
        }
}

// ---------------- kernel 4: output projection ----------------
// out[m][n] = sum_k Ocat[m][k] * Wo[n][k]   (Wo row-major is already B^T)
// grid: (128, 14), block 256
__global__ __launch_bounds__(256) void out_gemm(
    const short* __restrict__ A, const float* __restrict__ Wo, float* __restrict__ out)
{
    __shared__ short Ash[64 * 40];
    __shared__ short Bsh[64 * 40];
    const int m0 = blockIdx.x * 64;
    const int n0 = blockIdx.y * 64;

    const int tid = threadIdx.x;
    const int wave = tid >> 6, lane = tid & 63;
    const int quad = lane >> 4, l16 = lane & 15;
    const int wm = (wave >> 1) * 32, wn = (wave & 1) * 32;

    f32x4 acc[2][2] = {};

    const int ar = tid >> 2, ac = (tid & 3) * 8;
    const int nr0 = tid >> 3, kc0 = (tid & 7) * 4;
    const int nr1 = nr0 + 32;

    for (int k0 = 0; k0 < HIDDEN; k0 += 32) {
        bf16x8 av = *(const bf16x8*)(A + (m0 + ar) * HIDDEN + k0 + ac);
        float4 bv0 = *(const float4*)(Wo + (size_t)(n0 + nr0) * HIDDEN + k0 + kc0);
        float4 bv1 = *(const float4*)(Wo + (size_t)(n0 + nr1) * HIDDEN + k0 + kc0);
        __syncthreads();
        *(bf16x8*)(Ash + ar * 40 + ac) = av;
        short4 s0, s1;
        s0.x = f2bf(bv0.x); s0.y = f2bf(bv0.y); s0.z = f2bf(bv0.z); s0.w = f2bf(bv0.w);
        s1.x = f2bf(bv1.x); s1.y = f2bf(bv1.y); s1.z = f2bf(bv1.z); s1.w = f2bf(bv1.w);
        *(short4*)(Bsh + nr0 * 40 + kc0) = s0;
        *(short4*)(Bsh + nr1 * 40 + kc0) = s1;
        __syncthreads();
        bf16x8 af0 = *(const bf16x8*)(Ash + (wm + l16) * 40 + quad * 8);
        bf16x8 af1 = *(const bf16x8*)(Ash + (wm + 16 + l16) * 40 + quad * 8);
        bf16x8 bf0 = *(const bf16x8*)(Bsh + (wn + l16) * 40 + quad * 8);
        bf16x8 bf1 = *(const bf16x8*)(Bsh + (wn + 16 + l16) * 40 + quad * 8);
        acc[0][0] = __builtin_amdgcn_mfma_f32_16x16x32_bf16(af0, bf0, acc[0][0], 0, 0, 0);
        acc[0][1] = __builtin_amdgcn_mfma_f32_16x16x32_bf16(af0, bf1, acc[0][1], 0, 0, 0);
        acc[1][0] = __builtin_amdgcn_mfma_f32_16x16x32_bf16(af1, bf0, acc[1][0], 0, 0, 0);
        acc[1][1] = __builtin_amdgcn_mfma_f32_16x16x32_bf16(af1, bf1, acc[1][1], 0, 0, 0);
    }

    for (int mi = 0; mi < 2; mi++)
        for (int ni = 0; ni < 2; ni++)
            for (int r = 0; r < 4; r++) {
                int m = m0 + wm + mi * 16 + quad * 4 + r;
                int n = n0 + wn + ni * 16 + l16;
                out[(size_t)m * HIDDEN + n] = acc[mi][ni][r];
            }
}

extern "C" void kernel_launch(void* const* d_in, const int* in_sizes, int n_in,
                              void* d_out, int out_size, void* d_ws, size_t ws_size,
                              hipStream_t stream) {
    (void)in_sizes; (void)n_in; (void)out_size; (void)ws_size;
    const float* x  = (const float*)d_in[0];
    const float* Wq = (const float*)d_in[1];
    const float* Wk = (const float*)d_in[2];
    const float* Wv = (const float*)d_in[3];
    const float* Wo = (const float*)d_in[4];
    const int* iscp = (const int*)d_in[5];
    float* out = (float*)d_out;

    short* xb   = (short*)d_ws;              // 8192*896
    short* Qb   = xb  + (size_t)MTOT * HIDDEN;   // 7*8192*128
    short* Kb   = Qb  + (size_t)HEADS * MTOT * HDIM;
    short* Vtb  = Kb  + (size_t)HEADS * MTOT * HDIM;
    short* Ocat = Vtb + (size_t)HEADS * MTOT * HDIM;  // 8192*896

    cast_x_kernel<<<(MTOT * HIDDEN) / (256 * 4), 256, 0, stream>>>(x, xb);
    qkv_gemm<<<dim3(MTOT / 64, HDIM / 64, HEADS * 3), 256, 0, stream>>>(
        xb, Wq, Wk, Wv, Qb, Kb, Vtb);
    fano_attn<<<dim3(TT / 64, BB, HEADS), 256, 0, stream>>>(Qb, Kb, Vtb, Ocat, iscp);
    out_gemm<<<dim3(MTOT / 64, HIDDEN / 64), 256, 0, stream>>>(Ocat, Wo, out);
}